// Round 12
// baseline (47.063 us; speedup 1.0000x reference)
//
#include <hip/hip_runtime.h>
#include <hip/hip_fp16.h>

typedef unsigned short u16;
typedef unsigned int   u32;
typedef u32   u32x2  __attribute__((ext_vector_type(2)));
typedef u32   u32x4  __attribute__((ext_vector_type(4)));
typedef short short8 __attribute__((ext_vector_type(8)));
typedef float f32x4  __attribute__((ext_vector_type(4)));
typedef _Float16 half8 __attribute__((ext_vector_type(8)));

__device__ __forceinline__ u16 f2h(float f) { return __half_as_ushort(__float2half(f)); }
__device__ __forceinline__ f32x4 mfma16(short8 a, short8 b, f32x4 c) {
  return __builtin_amdgcn_mfma_f32_16x16x32_f16(
      __builtin_bit_cast(half8, a), __builtin_bit_cast(half8, b), c, 0, 0, 0);
}
__device__ __forceinline__ __half2 h2cast(u32 u) { return __builtin_bit_cast(__half2, u); }
__device__ __forceinline__ int refl(int v) { return v < 0 ? -v : (v > 63 ? 126 - v : v); }

// Barrier that does NOT drain vmcnt (cross-wave hazards are LDS-only).
__device__ __forceinline__ void softbar() {
  asm volatile("s_waitcnt lgkmcnt(0)" ::: "memory");
  __builtin_amdgcn_s_barrier();
  asm volatile("" ::: "memory");
}

// ---------------- fused prep: x NCHW f32 -> NHWC f16 ; weights -> MFMA order ----------------
__global__ __launch_bounds__(256) void prep_fused(const float* __restrict__ x,
                                                  const float* __restrict__ w_dc,
                                                  const float* __restrict__ w_off,
                                                  u16* __restrict__ xh,
                                                  u16* __restrict__ Wl2,
                                                  u16* __restrict__ Wol2) {
  int bid = blockIdx.x;
  int tid = threadIdx.x;
  if (bid < 512) {
    __shared__ float tile[128][65];
    int swz = (bid & 7) * 64 + (bid >> 3);
    int b = swz >> 6, h = swz & 63;
    for (int i = 0; i < 32; ++i) {
      int c = (tid >> 6) + i * 4;
      int w = tid & 63;
      tile[c][w] = x[(((size_t)b * 128 + c) * 64 + h) * 64 + w];
    }
    __syncthreads();
    u16* dst = xh + ((size_t)(b * 64 + h) * 64) * 128;
    for (int j = 0; j < 32; ++j) {
      int c = tid & 127;
      int w = (tid >> 7) + 2 * j;
      dst[w * 128 + c] = f2h(tile[c][w]);
    }
  } else {
    int idx = (bid - 512) * 256 + tid;        // 0..331775
    if (idx < 294912) {
      // Wl2 idx = (((kk*16+mt)*4+ks)*64+lane)*8+e : o=mt*16+(lane&15), c=ks*32+(lane>>4)*8+e
      int e = idx & 7, lane = (idx >> 3) & 63, ks = (idx >> 9) & 3;
      int mt = (idx >> 11) & 15, kk = idx >> 15;
      int o = mt * 16 + (lane & 15), c = ks * 32 + (lane >> 4) * 8 + e;
      Wl2[idx] = f2h(w_dc[(o * 128 + c) * 9 + kk]);
    } else {
      int i2 = idx - 294912;                  // 0..36863
      int e = i2 & 7, lane = (i2 >> 3) & 63, ks = (i2 >> 9) & 3;
      int mt = (i2 >> 11) & 1, kk = i2 >> 12;
      int co = mt * 16 + (lane & 15), c = ks * 32 + (lane >> 4) * 8 + e;
      Wol2[i2] = (co < 18) ? f2h(w_off[(co * 128 + c) * 9 + kk]) : (u16)0;
    }
  }
}

// ---------------- sampling-table entry (LDS, [kk][l 0..127]) ----------------
__device__ __forceinline__ void make_entry_lds(u32x4* __restrict__ tbl, int kk,
                                               int ho, int wo, int lq,
                                               float offy, float offx) {
  int ki = kk / 3, kj = kk - ki * 3;
  float py = offy + (float)(ho + ki - 1);
  float px = offx + (float)(wo + kj - 1);
  float fy0 = floorf(py), fx0 = floorf(px);
  int y0 = (int)fy0, x0 = (int)fx0;
  float fy = py - fy0, fx = px - fx0;
  float w11 = fy * fx, w10 = fy - w11, w01 = fx - w11, w00 = 1.f - fy - fx + w11;
  bool iy0 = (y0 >= 0) & (y0 < 64), iy1 = (y0 >= -1) & (y0 < 63);
  bool ix0 = (x0 >= 0) & (x0 < 64), ix1 = (x0 >= -1) & (x0 < 63);
  int y0c = min(max(y0, 0), 63), x0c = min(max(x0, 0), 63);
  u32 addr00 = (u32)((y0c * 64 + x0c) * 128);          // u16-element offset
  u32 dx = (x0 >= 0 && x0 < 63) ? 128u : 0u;
  u32 dy = (y0 >= 0 && y0 < 63) ? 8192u : 0u;
  u32 wA = (u32)f2h((iy0 && ix0) ? w00 : 0.f) | ((u32)f2h((iy0 && ix1) ? w01 : 0.f) << 16);
  u32 wB = (u32)f2h((iy1 && ix0) ? w10 : 0.f) | ((u32)f2h((iy1 && ix1) ? w11 : 0.f) << 16);
  u32x4 ent; ent.x = addr00; ent.y = dx | (dy << 16); ent.z = wA; ent.w = wB;
  tbl[kk * 128 + lq] = ent;
}

// ---------------- fused: 128l x 256co per block, 16 waves, 1 block/CU ----------------
__global__ __launch_bounds__(1024, 4) void deform_fused(
    const u16* __restrict__ xh, const u16* __restrict__ Wl2,
    const u16* __restrict__ Wol2, const float* __restrict__ b_off,
    const float* __restrict__ b_dc, float* __restrict__ out) {
  __shared__ union SCU {
    u16 slab[4][64][128];                // 65536 B (phase A: rows ho0-1..ho0+2)
    u16 cols[2][128][128];               // 65536 B (phase B dbuf)
  } sc;
  __shared__ u32x4 tbl[9 * 128];         // 18432 B (persists A->B)

  int bid = blockIdx.x;
  int b = bid & 7, t = bid >> 3;         // batch -> XCD ; t 0..31
  int ho0 = t * 2;
  int tid = threadIdx.x, lane = tid & 63, wv = tid >> 6;   // wv 0..15
  int ln15 = lane & 15, kg = lane >> 4;
  const u16* xb = xh + (size_t)b * 524288;

  // ================= phase A: stage 4-row slab once =================
  {
    u32x4 st[4];
#pragma unroll
    for (int i = 0; i < 4; ++i) {
      int T = tid + i * 1024;            // 0..4095
      int r = T >> 10, w = (T >> 4) & 63, cb = (T & 15) * 8;
      int hr = refl(ho0 - 1 + r);
      st[i] = *(const u32x4*)(xb + (hr * 64 + w) * 128 + cb);
    }
#pragma unroll
    for (int i = 0; i < 4; ++i) {
      int T = tid + i * 1024;
      int r = T >> 10, w = (T >> 4) & 63, cb = (T & 15) * 8;
      *(u32x4*)&sc.slab[r][w][cb ^ ((w & 7) << 3)] = st[i];
    }
  }
  __syncthreads();

  // ---- offset conv: M=32(pad18) x N=128; wave = (mtA, 16-l slice) ----
  int mtA = wv & 1;
  int lq = (wv >> 1) * 16 + ln15;        // 0..127
  int lh = lq >> 6, lw = lq & 63;
  f32x4 oacc = {0.f, 0.f, 0.f, 0.f};
  __builtin_amdgcn_s_setprio(1);
#pragma unroll
  for (int kk = 0; kk < 9; ++kk) {
    int ki = kk / 3, kj = kk - ki * 3;
    int j = refl(lw + kj - 1);
    int row = lh + ki;                   // 0..3
    const u16* wb = Wol2 + ((kk * 2 + mtA) * 4) * 512 + lane * 8;
    int sbj = (j & 7) << 3;
#pragma unroll
    for (int ks = 0; ks < 4; ++ks) {
      short8 af = *(const short8*)(wb + ks * 512);
      short8 bf = *(const short8*)&sc.slab[row][j][(ks * 32 + kg * 8) ^ sbj];
      oacc = mfma16(af, bf, oacc);
    }
  }
  __builtin_amdgcn_s_setprio(0);

  // ---- write sampling table (tbl does NOT alias slab) ----
  if (mtA == 0) {
    int kkA = 2 * kg, kkB = 2 * kg + 1;
    make_entry_lds(tbl, kkA, ho0 + lh, lw, lq, oacc[0] + b_off[2 * kkA], oacc[1] + b_off[2 * kkA + 1]);
    make_entry_lds(tbl, kkB, ho0 + lh, lw, lq, oacc[2] + b_off[2 * kkB], oacc[3] + b_off[2 * kkB + 1]);
  } else if (kg == 0) {
    make_entry_lds(tbl, 8, ho0 + lh, lw, lq, oacc[0] + b_off[16], oacc[1] + b_off[17]);
  }
  __syncthreads();                       // tbl visible + slab reads done (cols aliases slab)

  // ================= phase B: role split =================
  if (wv >= 8) {
    // ---------------- PRODUCER waves (8): gather + bilinear + ds_write ----------------
    int pt = tid & 511;                  // 0..511
    int tl = pt >> 4;                    // 0..31 ; tasks l = tl + i*32
    int tcl = (pt & 15) * 8;
    int swzc = tcl ^ ((tl & 7) << 3);    // (tl+32i)&7 == tl&7

    u32x4 gv[4][4];
    u32 gwA[4], gwB[4];
    auto gissue = [&](int g) {
#pragma unroll
      for (int i = 0; i < 4; ++i) {
        int l = tl + i * 32;
        u32x4 e = tbl[g * 128 + l];
        gwA[i] = e.z; gwB[i] = e.w;
        const u16* p = xb + e.x + tcl;
        u32 dxv = e.y & 0xffffu, dyv = e.y >> 16;
        gv[i][0] = *(const u32x4*)p;
        gv[i][1] = *(const u32x4*)(p + dxv);
        gv[i][2] = *(const u32x4*)(p + dyv);
        gv[i][3] = *(const u32x4*)(p + dyv + dxv);
      }
    };
    auto gwrite = [&](int dbuf) {
#pragma unroll
      for (int i = 0; i < 4; ++i) {
        int l = tl + i * 32;
        __half2 wA = h2cast(gwA[i]), wB = h2cast(gwB[i]);
        __half2 w00 = __half2half2(wA.x), w01 = __half2half2(wA.y);
        __half2 w10 = __half2half2(wB.x), w11 = __half2half2(wB.y);
        u32x4 pv;
#pragma unroll
        for (int wd = 0; wd < 4; ++wd) {
          __half2 r = __hmul2(h2cast(gv[i][0][wd]), w00);
          r = __hfma2(h2cast(gv[i][1][wd]), w01, r);
          r = __hfma2(h2cast(gv[i][2][wd]), w10, r);
          r = __hfma2(h2cast(gv[i][3][wd]), w11, r);
          pv[wd] = __builtin_bit_cast(u32, r);
        }
        *(u32x4*)&sc.cols[dbuf][l][swzc] = pv;
      }
    };

    gissue(0); gwrite(0);
    gissue(1);
    softbar();                           // B(0) ready; B(1) gathers in flight
    for (int kk = 0; kk < 9; ++kk) {
      int cur = kk & 1;
      if (kk < 8) gwrite(cur ^ 1);       // gathers issued a full step ago
      if (kk < 7) gissue(kk + 2);
      softbar();
    }
  } else {
    // ---------------- CONSUMER waves (8): wave = 64co x 64l ----------------
    int cg = wv & 3, lhc = wv >> 2;      // co-group, l-half
    f32x4 acc[4][4];
#pragma unroll
    for (int m = 0; m < 4; ++m)
#pragma unroll
      for (int n = 0; n < 4; ++n) acc[m][n] = (f32x4){0.f, 0.f, 0.f, 0.f};

    int swzb = (ln15 & 7) << 3;
    softbar();                           // B(0) ready
    for (int kk = 0; kk < 9; ++kk) {
      int cur = kk & 1;
      const u16* wb = Wl2 + (size_t)kk * 32768 + lane * 8;
      short8 ac[4], an[4];
#pragma unroll
      for (int m = 0; m < 4; ++m)
        ac[m] = *(const short8*)(wb + (size_t)((cg * 4 + m) * 4) * 512);
#pragma unroll
      for (int ks = 0; ks < 4; ++ks) {
        if (ks < 3) {
#pragma unroll
          for (int m = 0; m < 4; ++m)
            an[m] = *(const short8*)(wb + (size_t)((cg * 4 + m) * 4 + ks + 1) * 512);
        }
        __builtin_amdgcn_s_setprio(1);
#pragma unroll
        for (int nt = 0; nt < 4; ++nt) {
          int l = lhc * 64 + nt * 16 + ln15;
          short8 bf = *(const short8*)&sc.cols[cur][l][(ks * 32 + kg * 8) ^ swzb];
#pragma unroll
          for (int m = 0; m < 4; ++m)
            acc[m][nt] = mfma16(ac[m], bf, acc[m][nt]);
        }
        __builtin_amdgcn_s_setprio(0);
        if (ks < 3) {
#pragma unroll
          for (int m = 0; m < 4; ++m) ac[m] = an[m];
        }
      }
      softbar();
    }

    // epilogue: wave (cg,lhc) owns co [cg*64, cg*64+64), l [lhc*64, lhc*64+64)
#pragma unroll
    for (int m = 0; m < 4; ++m) {
#pragma unroll
      for (int r = 0; r < 4; ++r) {
        int o = cg * 64 + m * 16 + kg * 4 + r;
        float bias = b_dc[o];
        size_t base = ((size_t)(b * 256 + o)) * 4096 + ho0 * 64 + lhc * 64;
#pragma unroll
        for (int nt = 0; nt < 4; ++nt) {
          out[base + nt * 16 + ln15] = acc[m][nt][r] + bias;
        }
      }
    }
  }
}

extern "C" void kernel_launch(void* const* d_in, const int* in_sizes, int n_in,
                              void* d_out, int out_size, void* d_ws, size_t ws_size,
                              hipStream_t stream) {
  const float* x     = (const float*)d_in[0];
  const float* w_off = (const float*)d_in[1];
  const float* b_off = (const float*)d_in[2];
  const float* w_dc  = (const float*)d_in[3];
  const float* b_dc  = (const float*)d_in[4];
  float* out = (float*)d_out;
  char* ws = (char*)d_ws;
  u16* xh   = (u16*)ws;                                   // 8,388,608 B
  u16* Wl2  = (u16*)(ws + 8388608);                       //   589,824 B
  u16* Wol2 = (u16*)(ws + 8388608 + 589824);              //    73,728 B (tot 9.05 MB)
  prep_fused  <<<dim3(1808), dim3(256), 0, stream>>>(x, w_dc, w_off, xh, Wl2, Wol2);
  deform_fused<<<dim3(256),  dim3(1024), 0, stream>>>(xh, Wl2, Wol2, b_off, b_dc, out);
}